// Round 7
// baseline (50.472 us; speedup 1.0000x reference)
//
#include <hip/hip_runtime.h>

// Problem constants
#define NT 64        // trees
#define NF 1024      // features per tree
#define NB 1024      // batch (GEMM M)
#define ND 2048      // d width (GEMM K)
#define NTP 32       // padded columns per tree
#define NN2 (NT * NTP)   // 2048 = padded GEMM N
#define NP 27        // partials per (b, 4-tree group)
#define NW2ROW 1027
#define BK 64        // GEMM K-tile
#define NSCAT 2048   // scatter blocks (64 t x 32 k)
#define NCONV 1024   // convert blocks

typedef __attribute__((ext_vector_type(8))) short short8;
typedef __attribute__((ext_vector_type(4))) float f32x4;

static __device__ __forceinline__ unsigned short f2bf(float x) {
    unsigned u = __float_as_uint(x);
    unsigned r = (u + 0x7FFFu + ((u >> 16) & 1u)) >> 16;   // RNE
    return (unsigned short)r;
}

// ---------------------------------------------------------------------------
// prep: blocks [0, NSCAT) build padded folded weights Wf[n][j] (bf16),
// n = t*32 + k (k in [21,32) rows zeroed); blocks [NSCAT, NSCAT+NCONV)
// convert d -> bf16.
// ---------------------------------------------------------------------------
__global__ __launch_bounds__(256) void prep_kernel(
    const int* __restrict__ idx, const float* __restrict__ w_clc,
    const float* __restrict__ w1, const float* __restrict__ w2,
    const float* __restrict__ d, unsigned short* __restrict__ Wf,
    unsigned short* __restrict__ db)
{
    __shared__ float tile[ND];   // 8 KB
    int bid = blockIdx.x;
    int tid = threadIdx.x;

    if (bid < NSCAT) {
        int t = bid >> 5, k = bid & 31;   // row n == bid
        if (k >= 21) {                     // pad row: zeros
            uint4 z = make_uint4(0, 0, 0, 0);
            *(uint4*)&Wf[(size_t)bid * ND + tid * 8] = z;
            return;
        }
        for (int i = tid; i < ND; i += 256) tile[i] = 0.f;
        __syncthreads();

        const float* src; int stride;
        if (k < 2)      { src = w_clc + (size_t)t * 2048 + k;            stride = 2;  }
        else if (k < 5) { src = w1    + (size_t)t * 3072 + (k - 2);      stride = 3;  }
        else            { src = w2    + (size_t)t * NW2ROW * 16 + (k-5); stride = 16; }

        const int* idt = idx + t * NF;
        for (int f = tid; f < NF; f += 256)
            atomicAdd(&tile[idt[f]], src[(size_t)f * stride]);
        __syncthreads();

        int i8 = tid * 8;
        union { unsigned short u[8]; uint4 v; } pk;
#pragma unroll
        for (int e = 0; e < 8; ++e) pk.u[e] = f2bf(tile[i8 + e]);
        *(uint4*)&Wf[(size_t)bid * ND + i8] = pk.v;
    } else {
        int cb = bid - NSCAT;
        int i8 = (cb * 256 + tid) * 8;
        float4 a = *(const float4*)&d[i8];
        float4 b = *(const float4*)&d[i8 + 4];
        union { unsigned short u[8]; uint4 v; } pk;
        pk.u[0] = f2bf(a.x); pk.u[1] = f2bf(a.y); pk.u[2] = f2bf(a.z); pk.u[3] = f2bf(a.w);
        pk.u[4] = f2bf(b.x); pk.u[5] = f2bf(b.y); pk.u[6] = f2bf(b.z); pk.u[7] = f2bf(b.w);
        *(uint4*)&db[i8] = pk.v;
    }
}

// ---------------------------------------------------------------------------
// Fused GEMM + epilogue. Grid (16 n-tiles, 8 m-tiles), block 256 (4 waves).
// Tile 128 b x 128 n (= 4 trees), full K = 2048 (32 kt of BK=64).
// Wave wv: wr=wv>>1 (m-half, 64 rows), wc=wv&1 (n-half, 64 cols), 4x4
// 16x16x32 fragments -> 64x64 output per wave (32 FLOP / LDS byte).
// LDS tiles are XOR-swizzled on 16B granules (slot ^= row&7): staging keeps
// a LINEAR LDS dest (global_load_lds constraint, m104) and pre-swizzles the
// GLOBAL source slot (m173/m201); ds_read applies the same XOR -> <=2-way
// bank access (free, m136) instead of 16-way.
// After K-loop: C -> LDS (Cl[128][129], aliased over staging), in-block
// per-(b,tree) softmax/gate epilogue, 4 trees combined -> ptl2[nb][27][b].
// ---------------------------------------------------------------------------
__global__ __launch_bounds__(256, 1) void fused_kernel(
    const unsigned short* __restrict__ A,    // db [1024][2048]
    const unsigned short* __restrict__ Bm,   // Wf [2048][2048]
    const float* __restrict__ b_clc, const float* __restrict__ b1,
    const float* __restrict__ b2, const float* __restrict__ w2,
    const int* __restrict__ cc, float* __restrict__ ptl2)
{
    __shared__ __align__(16) char smem[79872];
    unsigned short (*As)[128][BK] = (unsigned short(*)[128][BK])smem;            // 2x16 KB
    unsigned short (*Bs)[128][BK] = (unsigned short(*)[128][BK])(smem + 32768);  // 2x16 KB
    float* Cl  = (float*)smem;              // [128][129] = 66,048 B (alias)
    float* red = (float*)(smem + 66048);    // [27][128]  = 13,824 B

    int tid = threadIdx.x;
    int lane = tid & 63;
    int wv = tid >> 6;          // 0..3
    int wr = wv >> 1;           // m-half
    int wc = wv & 1;            // n-half
    int nb = blockIdx.x;        // n-tile (4 trees)
    int mb = blockIdx.y;        // m-tile
    int m0 = mb * 128;
    int n0 = nb * 128;
    int r0 = lane & 15;
    int kq = lane >> 4;
    int sx = r0 & 7;                    // read-side XOR key
    int sl0 = ((kq) ^ sx) * 8;          // ks=0 swizzled element offset
    int sl1 = ((4 + kq) ^ sx) * 8;      // ks=1

    f32x4 acc[4][4];
#pragma unroll
    for (int mi = 0; mi < 4; ++mi)
#pragma unroll
        for (int ni = 0; ni < 4; ++ni) acc[mi][ni] = (f32x4)0.f;

    // Staging: 1024 16B-chunks per matrix tile (128 rows x 8 slots); LDS dest
    // linear in chunk; global source slot pre-swizzled (c ^ (row&7)).
#define STAGE(buf, kt)                                                          \
    {                                                                           \
        size_t koff = (size_t)(kt) * BK;                                        \
        _Pragma("unroll")                                                       \
        for (int p = 0; p < 4; ++p) {                                           \
            int chunk = p * 256 + tid;                                          \
            int row = chunk >> 3, c = chunk & 7;                                \
            int csw = (c ^ (row & 7)) * 8;                                      \
            const unsigned short* ga = A + (size_t)(m0 + row) * ND + koff + csw;\
            __builtin_amdgcn_global_load_lds(                                   \
                (const __attribute__((address_space(1))) void*)ga,              \
                (__attribute__((address_space(3))) void*)&As[buf][row][c * 8],  \
                16, 0, 0);                                                      \
        }                                                                       \
        _Pragma("unroll")                                                       \
        for (int p = 0; p < 4; ++p) {                                           \
            int chunk = p * 256 + tid;                                          \
            int row = chunk >> 3, c = chunk & 7;                                \
            int csw = (c ^ (row & 7)) * 8;                                      \
            const unsigned short* gb = Bm + (size_t)(n0 + row) * ND + koff + csw;\
            __builtin_amdgcn_global_load_lds(                                   \
                (const __attribute__((address_space(1))) void*)gb,              \
                (__attribute__((address_space(3))) void*)&Bs[buf][row][c * 8],  \
                16, 0, 0);                                                      \
        }                                                                       \
    }

    STAGE(0, 0);
    __syncthreads();

    int cur = 0;
    for (int kt = 0; kt < 32; ++kt) {
        if (kt < 31) STAGE(cur ^ 1, kt + 1);

        short8 af[4][2], bf[4][2];   // [rep][ksub]
#pragma unroll
        for (int mi = 0; mi < 4; ++mi) {
            af[mi][0] = *(const short8*)&As[cur][wr*64 + mi*16 + r0][sl0];
            af[mi][1] = *(const short8*)&As[cur][wr*64 + mi*16 + r0][sl1];
        }
#pragma unroll
        for (int ni = 0; ni < 4; ++ni) {
            bf[ni][0] = *(const short8*)&Bs[cur][wc*64 + ni*16 + r0][sl0];
            bf[ni][1] = *(const short8*)&Bs[cur][wc*64 + ni*16 + r0][sl1];
        }
#pragma unroll
        for (int ks = 0; ks < 2; ++ks)
#pragma unroll
            for (int mi = 0; mi < 4; ++mi)
#pragma unroll
                for (int ni = 0; ni < 4; ++ni)
                    acc[mi][ni] = __builtin_amdgcn_mfma_f32_16x16x32_bf16(
                        af[mi][ks], bf[ni][ks], acc[mi][ni], 0, 0, 0);
        __syncthreads();
        cur ^= 1;
    }
#undef STAGE

    // C -> LDS. D layout (proven R4): b = wr*64+mi*16+kq*4+q, n = wc*64+ni*16+r0.
    // Cl stride 129 (odd) -> near-conflict-free both directions.
#pragma unroll
    for (int mi = 0; mi < 4; ++mi)
#pragma unroll
        for (int ni = 0; ni < 4; ++ni) {
            int n = wc * 64 + ni * 16 + r0;
            int bl = wr * 64 + mi * 16 + kq * 4;
#pragma unroll
            for (int q = 0; q < 4; ++q)
                Cl[(bl + q) * 129 + n] = acc[mi][ni][q];
        }
    __syncthreads();

    // ---- epilogue: 256 threads; thread (h=tid>>7, bl=tid&127) handles trees
    // {2h, 2h+1} of this block's 4; accumulates s[27]; halves combine via red.
    int h  = tid >> 7;
    int bl = tid & 127;
    float s[NP];
#pragma unroll
    for (int k = 0; k < NP; ++k) s[k] = 0.f;

#pragma unroll
    for (int p = 0; p < 2; ++p) {
        int tl = h * 2 + p;
        int t  = nb * 4 + tl;

        float a21[21];
#pragma unroll
        for (int k = 0; k < 21; ++k) a21[k] = Cl[bl * 129 + tl * 32 + k];

        float L0 = a21[0] + b_clc[t * 2 + 0];
        float L1 = a21[1] + b_clc[t * 2 + 1];
        float mm = fmaxf(L0, L1);
        float e0 = __expf(L0 - mm), e1 = __expf(L1 - mm);
        float gate = e1 / (e0 + e1);

        float l1v[3];
        float m1 = -3.0e38f;
#pragma unroll
        for (int c = 0; c < 3; ++c) {
            l1v[c] = a21[2 + c] + b1[t * 3 + c];
            m1 = fmaxf(m1, l1v[c]);
        }
        float p1[3]; float S1 = 0.f;
#pragma unroll
        for (int c = 0; c < 3; ++c) { p1[c] = __expf(l1v[c] - m1); S1 += p1[c]; }
        float invS1g = gate / S1;

        float r0f = fmaxf(l1v[0], 0.f);
        float r1f = fmaxf(l1v[1], 0.f);
        float r2f = fmaxf(l1v[2], 0.f);

        const float* w2t = w2 + ((size_t)t * NW2ROW + NF) * 16;
        float l2[16]; float m2 = -3.0e38f;
#pragma unroll
        for (int nn = 0; nn < 16; ++nn) {
            float v = a21[5 + nn] + b2[t * 16 + nn];
            v = fmaf(r0f, w2t[nn], v);
            v = fmaf(r1f, w2t[16 + nn], v);
            v = fmaf(r2f, w2t[32 + nn], v);
            l2[nn] = v;
            m2 = fmaxf(m2, v);
        }
        float S2 = 0.f; float p2[16];
#pragma unroll
        for (int nn = 0; nn < 16; ++nn) { p2[nn] = __expf(l2[nn] - m2); S2 += p2[nn]; }
        float invS2g = gate * __frcp_rn(S2);

#pragma unroll
        for (int c = 0; c < 3; ++c) {
            int sl = cc[t * 3 + c];
            float pc = p1[c] * invS1g;
#pragma unroll
            for (int x = 0; x < 5; ++x) {
                if (sl == x) { s[x] += pc; s[5 + x] += gate; }
            }
        }
#pragma unroll
        for (int nn = 0; nn < 16; ++nn) s[10 + nn] += p2[nn] * invS2g;
        s[26] += gate;
    }

    if (h == 1) {
#pragma unroll
        for (int k = 0; k < NP; ++k) red[k * 128 + bl] = s[k];
    }
    __syncthreads();
    if (h != 0) return;

    float* pt = ptl2 + (size_t)nb * NP * NB + m0 + bl;
#pragma unroll
    for (int k = 0; k < NP; ++k)
        pt[(size_t)k * NB] = s[k] + red[k * 128 + bl];
}

// ---------------------------------------------------------------------------
// Finalize: reduce 16 n-tile slices (fixed order), normalize, write out[b][21].
// Grid 16, block 256 (4 waves; wave w owns slices w, w+4, w+8, w+12).
// ---------------------------------------------------------------------------
__global__ __launch_bounds__(256) void finalize_kernel(
    const float* __restrict__ ptl2, float* __restrict__ out)
{
    int lane = threadIdx.x & 63;
    int w = threadIdx.x >> 6;           // 0..3
    int b = blockIdx.x * 64 + lane;

    float s[NP];
#pragma unroll
    for (int k = 0; k < NP; ++k) s[k] = 0.f;
#pragma unroll
    for (int i = 0; i < 4; ++i) {
        const float* pt = ptl2 + (size_t)(w + i * 4) * NP * NB + b;
#pragma unroll
        for (int k = 0; k < NP; ++k) s[k] += pt[(size_t)k * NB];
    }

    __shared__ float red[3][NP][64];
    if (w > 0) {
#pragma unroll
        for (int k = 0; k < NP; ++k) red[w - 1][k][lane] = s[k];
    }
    __syncthreads();
    if (w != 0) return;
#pragma unroll
    for (int r = 0; r < 3; ++r)
#pragma unroll
        for (int k = 0; k < NP; ++k) s[k] += red[r][k][lane];

    float* ob = out + (size_t)b * 21;
#pragma unroll
    for (int x = 0; x < 5; ++x) {
        float c = s[5 + x];
        ob[x] = (c > 0.f) ? (s[x] / c) : 0.f;
    }
    float invg = 1.f / s[26];
#pragma unroll
    for (int n = 0; n < 16; ++n) ob[5 + n] = s[10 + n] * invg;
}

// ---------------------------------------------------------------------------
extern "C" void kernel_launch(void* const* d_in, const int* in_sizes, int n_in,
                              void* d_out, int out_size, void* d_ws, size_t ws_size,
                              hipStream_t stream)
{
    const float* d     = (const float*)d_in[0];
    const int*   idx   = (const int*)  d_in[1];
    const int*   cc    = (const int*)  d_in[2];
    const float* w_clc = (const float*)d_in[3];
    const float* b_clc = (const float*)d_in[4];
    const float* w1    = (const float*)d_in[5];
    const float* b1    = (const float*)d_in[6];
    const float* w2    = (const float*)d_in[7];
    const float* b2    = (const float*)d_in[8];
    float* out = (float*)d_out;

    // ws layout
    unsigned short* Wf = (unsigned short*)d_ws;            // [2048][2048] bf16 = 8 MB
    unsigned short* db = Wf + (size_t)NN2 * ND;            // [1024][2048] bf16 = 4 MB
    float* ptl2 = (float*)(db + (size_t)NB * ND);          // [16][27][1024] f32

    prep_kernel<<<NSCAT + NCONV, 256, 0, stream>>>(idx, w_clc, w1, w2, d, Wf, db);
    fused_kernel<<<dim3(16, 8), 256, 0, stream>>>(db, Wf, b_clc, b1, b2, w2, cc, ptl2);
    finalize_kernel<<<16, 256, 0, stream>>>(ptl2, out);
}

// Round 8
// 44.116 us; speedup vs baseline: 1.1441x; 1.1441x over previous
//
#include <hip/hip_runtime.h>

// Problem constants
#define NT 64        // trees
#define NF 1024      // features per tree
#define NB 1024      // batch (GEMM M)
#define ND 2048      // d width (GEMM K)
#define NTP 32       // padded columns per tree
#define NN2 (NT * NTP)   // 2048 = padded GEMM N
#define NP 27        // partials per (b, 4-tree group)
#define NW2ROW 1027
#define BK 64        // GEMM K-tile
#define BM 64        // m-tile (batch rows per block)
#define BN 128       // n-tile (4 trees per block)
#define NSCAT 2048   // scatter blocks (64 t x 32 k)
#define NCONV 1024   // convert blocks

typedef __attribute__((ext_vector_type(8))) short short8;
typedef __attribute__((ext_vector_type(4))) float f32x4;

static __device__ __forceinline__ unsigned short f2bf(float x) {
    unsigned u = __float_as_uint(x);
    unsigned r = (u + 0x7FFFu + ((u >> 16) & 1u)) >> 16;   // RNE
    return (unsigned short)r;
}

// ---------------------------------------------------------------------------
// prep: blocks [0, NSCAT) build padded folded weights Wf[n][j] (bf16),
// n = t*32 + k (k in [21,32) rows zeroed); blocks [NSCAT, NSCAT+NCONV)
// convert d -> bf16.
// ---------------------------------------------------------------------------
__global__ __launch_bounds__(256) void prep_kernel(
    const int* __restrict__ idx, const float* __restrict__ w_clc,
    const float* __restrict__ w1, const float* __restrict__ w2,
    const float* __restrict__ d, unsigned short* __restrict__ Wf,
    unsigned short* __restrict__ db)
{
    __shared__ float tile[ND];   // 8 KB
    int bid = blockIdx.x;
    int tid = threadIdx.x;

    if (bid < NSCAT) {
        int t = bid >> 5, k = bid & 31;   // row n == bid
        if (k >= 21) {                     // pad row: zeros
            uint4 z = make_uint4(0, 0, 0, 0);
            *(uint4*)&Wf[(size_t)bid * ND + tid * 8] = z;
            return;
        }
        for (int i = tid; i < ND; i += 256) tile[i] = 0.f;
        __syncthreads();

        const float* src; int stride;
        if (k < 2)      { src = w_clc + (size_t)t * 2048 + k;            stride = 2;  }
        else if (k < 5) { src = w1    + (size_t)t * 3072 + (k - 2);      stride = 3;  }
        else            { src = w2    + (size_t)t * NW2ROW * 16 + (k-5); stride = 16; }

        const int* idt = idx + t * NF;
        for (int f = tid; f < NF; f += 256)
            atomicAdd(&tile[idt[f]], src[(size_t)f * stride]);
        __syncthreads();

        int i8 = tid * 8;
        union { unsigned short u[8]; uint4 v; } pk;
#pragma unroll
        for (int e = 0; e < 8; ++e) pk.u[e] = f2bf(tile[i8 + e]);
        *(uint4*)&Wf[(size_t)bid * ND + i8] = pk.v;
    } else {
        int cb = bid - NSCAT;
        int i8 = (cb * 256 + tid) * 8;
        float4 a = *(const float4*)&d[i8];
        float4 b = *(const float4*)&d[i8 + 4];
        union { unsigned short u[8]; uint4 v; } pk;
        pk.u[0] = f2bf(a.x); pk.u[1] = f2bf(a.y); pk.u[2] = f2bf(a.z); pk.u[3] = f2bf(a.w);
        pk.u[4] = f2bf(b.x); pk.u[5] = f2bf(b.y); pk.u[6] = f2bf(b.z); pk.u[7] = f2bf(b.w);
        *(uint4*)&db[i8] = pk.v;
    }
}

// ---------------------------------------------------------------------------
// Fused GEMM + epilogue. Grid (16 n-tiles, 16 m-tiles) = 256 blocks (1/CU,
// full chip), block 512 = 8 waves (2/SIMD). Tile 64 b x 128 n (4 trees),
// full K = 2048 (32 kt of BK=64). Wave wv: wr=wv&1 (m-half of 32),
// wq=wv>>1 (n-quarter of 32); 2x2 16x16x32 fragments per wave.
// LDS reads/writes XOR-swizzled on 16B granules (slot ^= row&7): staging
// keeps a LINEAR LDS dest (global_load_lds constraint) and pre-swizzles the
// GLOBAL source slot; ds_read applies the same XOR -> conflict-free.
// After K-loop: C -> LDS Cl[64][129] (alias), per-(b,tree) epilogue with
// wave-uniform tree (tid>>6 = tree, lane = b), 4 trees combined via red,
// write ptl2[nb][27][b].
// ---------------------------------------------------------------------------
__global__ __launch_bounds__(512, 1) void fused_kernel(
    const unsigned short* __restrict__ A,    // db [1024][2048]
    const unsigned short* __restrict__ Bm,   // Wf [2048][2048]
    const float* __restrict__ b_clc, const float* __restrict__ b1,
    const float* __restrict__ b2, const float* __restrict__ w2,
    const int* __restrict__ cc, float* __restrict__ ptl2)
{
    __shared__ __align__(16) char smem[53760];
    unsigned short (*As)[BM][BK] = (unsigned short(*)[BM][BK])smem;             // 2x8 KB
    unsigned short (*Bs)[BN][BK] = (unsigned short(*)[BN][BK])(smem + 16384);   // 2x16 KB
    float* Cl  = (float*)smem;              // [64][129] = 33,024 B (alias)
    float* red = (float*)(smem + 33024);    // [3][27][64] = 20,736 B

    int tid = threadIdx.x;
    int lane = tid & 63;
    int wv = tid >> 6;          // 0..7
    int wr = wv & 1;            // m-half (32 rows)
    int wq = wv >> 1;           // n-quarter (32 cols)
    int nb = blockIdx.x;        // n-tile (4 trees)
    int mb = blockIdx.y;        // m-tile (64 b)
    int m0 = mb * BM;
    int n0 = nb * BN;
    int r0 = lane & 15;
    int kq = lane >> 4;
    int sx = r0 & 7;                        // read-side XOR key
    int sl0 = ((0 * 4 + kq) ^ sx) * 8;      // ks=0 swizzled element offset
    int sl1 = ((1 * 4 + kq) ^ sx) * 8;      // ks=1

    f32x4 acc[2][2];
#pragma unroll
    for (int mi = 0; mi < 2; ++mi)
#pragma unroll
        for (int ni = 0; ni < 2; ++ni) acc[mi][ni] = (f32x4)0.f;

    // Staging: A 512 chunks (64 rows x 8 slots), B 1024 chunks (128 x 8);
    // LDS dest linear; global source slot pre-swizzled (c ^ (row&7)).
#define STAGE(buf, kt)                                                          \
    {                                                                           \
        size_t koff = (size_t)(kt) * BK;                                        \
        {                                                                       \
            int row = tid >> 3, c = tid & 7;                                    \
            int csw = (c ^ (row & 7)) * 8;                                      \
            const unsigned short* ga = A + (size_t)(m0 + row) * ND + koff + csw;\
            __builtin_amdgcn_global_load_lds(                                   \
                (const __attribute__((address_space(1))) void*)ga,              \
                (__attribute__((address_space(3))) void*)&As[buf][row][c * 8],  \
                16, 0, 0);                                                      \
        }                                                                       \
        _Pragma("unroll")                                                       \
        for (int p = 0; p < 2; ++p) {                                           \
            int chunk = p * 512 + tid;                                          \
            int row = chunk >> 3, c = chunk & 7;                                \
            int csw = (c ^ (row & 7)) * 8;                                      \
            const unsigned short* gb = Bm + (size_t)(n0 + row) * ND + koff + csw;\
            __builtin_amdgcn_global_load_lds(                                   \
                (const __attribute__((address_space(1))) void*)gb,              \
                (__attribute__((address_space(3))) void*)&Bs[buf][row][c * 8],  \
                16, 0, 0);                                                      \
        }                                                                       \
    }

    STAGE(0, 0);
    __syncthreads();

    int cur = 0;
    for (int kt = 0; kt < 32; ++kt) {
        if (kt < 31) STAGE(cur ^ 1, kt + 1);

        short8 af[2][2], bf[2][2];   // [rep][ksub]
#pragma unroll
        for (int mi = 0; mi < 2; ++mi) {
            af[mi][0] = *(const short8*)&As[cur][wr*32 + mi*16 + r0][sl0];
            af[mi][1] = *(const short8*)&As[cur][wr*32 + mi*16 + r0][sl1];
        }
#pragma unroll
        for (int ni = 0; ni < 2; ++ni) {
            bf[ni][0] = *(const short8*)&Bs[cur][wq*32 + ni*16 + r0][sl0];
            bf[ni][1] = *(const short8*)&Bs[cur][wq*32 + ni*16 + r0][sl1];
        }
#pragma unroll
        for (int ks = 0; ks < 2; ++ks)
#pragma unroll
            for (int mi = 0; mi < 2; ++mi)
#pragma unroll
                for (int ni = 0; ni < 2; ++ni)
                    acc[mi][ni] = __builtin_amdgcn_mfma_f32_16x16x32_bf16(
                        af[mi][ks], bf[ni][ks], acc[mi][ni], 0, 0, 0);
        __syncthreads();
        cur ^= 1;
    }
#undef STAGE

    // C -> LDS. D layout (verified): b = wr*32+mi*16+kq*4+q, n = wq*32+ni*16+r0.
    // Cl stride 129 (odd) -> <=2-way banks both directions.
#pragma unroll
    for (int mi = 0; mi < 2; ++mi)
#pragma unroll
        for (int ni = 0; ni < 2; ++ni) {
            int n = wq * 32 + ni * 16 + r0;
            int bl = wr * 32 + mi * 16 + kq * 4;
#pragma unroll
            for (int q = 0; q < 4; ++q)
                Cl[(bl + q) * 129 + n] = acc[mi][ni][q];
        }
    __syncthreads();

    // ---- epilogue: waves 0..3 = trees 0..3 (wave-uniform t), lane = b ----
    int tl = tid >> 6;          // 0..7; trees are 0..3
    int bl = lane;
    float s[NP];
#pragma unroll
    for (int k = 0; k < NP; ++k) s[k] = 0.f;

    if (tl < 4) {
        int t = nb * 4 + tl;

        float a21[21];
#pragma unroll
        for (int k = 0; k < 21; ++k) a21[k] = Cl[bl * 129 + tl * 32 + k];

        float L0 = a21[0] + b_clc[t * 2 + 0];
        float L1 = a21[1] + b_clc[t * 2 + 1];
        float mm = fmaxf(L0, L1);
        float e0 = __expf(L0 - mm), e1 = __expf(L1 - mm);
        float gate = e1 / (e0 + e1);

        float l1v[3];
        float m1 = -3.0e38f;
#pragma unroll
        for (int c = 0; c < 3; ++c) {
            l1v[c] = a21[2 + c] + b1[t * 3 + c];
            m1 = fmaxf(m1, l1v[c]);
        }
        float p1[3]; float S1 = 0.f;
#pragma unroll
        for (int c = 0; c < 3; ++c) { p1[c] = __expf(l1v[c] - m1); S1 += p1[c]; }
        float invS1g = gate / S1;

        float r0f = fmaxf(l1v[0], 0.f);
        float r1f = fmaxf(l1v[1], 0.f);
        float r2f = fmaxf(l1v[2], 0.f);

        const float* w2t = w2 + ((size_t)t * NW2ROW + NF) * 16;
        float l2[16]; float m2 = -3.0e38f;
#pragma unroll
        for (int nn = 0; nn < 16; ++nn) {
            float v = a21[5 + nn] + b2[t * 16 + nn];
            v = fmaf(r0f, w2t[nn], v);
            v = fmaf(r1f, w2t[16 + nn], v);
            v = fmaf(r2f, w2t[32 + nn], v);
            l2[nn] = v;
            m2 = fmaxf(m2, v);
        }
        float S2 = 0.f; float p2[16];
#pragma unroll
        for (int nn = 0; nn < 16; ++nn) { p2[nn] = __expf(l2[nn] - m2); S2 += p2[nn]; }
        float invS2g = gate * __frcp_rn(S2);

#pragma unroll
        for (int c = 0; c < 3; ++c) {
            int sl = cc[t * 3 + c];
            float pc = p1[c] * invS1g;
#pragma unroll
            for (int x = 0; x < 5; ++x) {
                if (sl == x) { s[x] += pc; s[5 + x] += gate; }
            }
        }
#pragma unroll
        for (int nn = 0; nn < 16; ++nn) s[10 + nn] += p2[nn] * invS2g;
        s[26] += gate;
    }

    if (tl >= 1 && tl < 4) {
        float* rw = red + (size_t)(tl - 1) * NP * 64;
#pragma unroll
        for (int k = 0; k < NP; ++k) rw[k * 64 + bl] = s[k];
    }
    __syncthreads();
    if (tl != 0) return;

#pragma unroll
    for (int r = 0; r < 3; ++r)
#pragma unroll
        for (int k = 0; k < NP; ++k) s[k] += red[(size_t)r * NP * 64 + k * 64 + bl];

    float* pt = ptl2 + (size_t)nb * NP * NB + m0 + bl;
#pragma unroll
    for (int k = 0; k < NP; ++k)
        pt[(size_t)k * NB] = s[k];
}

// ---------------------------------------------------------------------------
// Finalize: reduce 16 n-tile slices (fixed order), normalize, write out[b][21].
// Grid 16, block 256 (4 waves; wave w owns slices w, w+4, w+8, w+12).
// ---------------------------------------------------------------------------
__global__ __launch_bounds__(256) void finalize_kernel(
    const float* __restrict__ ptl2, float* __restrict__ out)
{
    int lane = threadIdx.x & 63;
    int w = threadIdx.x >> 6;           // 0..3
    int b = blockIdx.x * 64 + lane;

    float s[NP];
#pragma unroll
    for (int k = 0; k < NP; ++k) s[k] = 0.f;
#pragma unroll
    for (int i = 0; i < 4; ++i) {
        const float* pt = ptl2 + (size_t)(w + i * 4) * NP * NB + b;
#pragma unroll
        for (int k = 0; k < NP; ++k) s[k] += pt[(size_t)k * NB];
    }

    __shared__ float red[3][NP][64];
    if (w > 0) {
#pragma unroll
        for (int k = 0; k < NP; ++k) red[w - 1][k][lane] = s[k];
    }
    __syncthreads();
    if (w != 0) return;
#pragma unroll
    for (int r = 0; r < 3; ++r)
#pragma unroll
        for (int k = 0; k < NP; ++k) s[k] += red[r][k][lane];

    float* ob = out + (size_t)b * 21;
#pragma unroll
    for (int x = 0; x < 5; ++x) {
        float c = s[5 + x];
        ob[x] = (c > 0.f) ? (s[x] / c) : 0.f;
    }
    float invg = 1.f / s[26];
#pragma unroll
    for (int n = 0; n < 16; ++n) ob[5 + n] = s[10 + n] * invg;
}

// ---------------------------------------------------------------------------
extern "C" void kernel_launch(void* const* d_in, const int* in_sizes, int n_in,
                              void* d_out, int out_size, void* d_ws, size_t ws_size,
                              hipStream_t stream)
{
    const float* d     = (const float*)d_in[0];
    const int*   idx   = (const int*)  d_in[1];
    const int*   cc    = (const int*)  d_in[2];
    const float* w_clc = (const float*)d_in[3];
    const float* b_clc = (const float*)d_in[4];
    const float* w1    = (const float*)d_in[5];
    const float* b1    = (const float*)d_in[6];
    const float* w2    = (const float*)d_in[7];
    const float* b2    = (const float*)d_in[8];
    float* out = (float*)d_out;

    // ws layout
    unsigned short* Wf = (unsigned short*)d_ws;            // [2048][2048] bf16 = 8 MB
    unsigned short* db = Wf + (size_t)NN2 * ND;            // [1024][2048] bf16 = 4 MB
    float* ptl2 = (float*)(db + (size_t)NB * ND);          // [16][27][1024] f32

    prep_kernel<<<NSCAT + NCONV, 256, 0, stream>>>(idx, w_clc, w1, w2, d, Wf, db);
    fused_kernel<<<dim3(16, 16), 512, 0, stream>>>(db, Wf, b_clc, b1, b2, w2, cc, ptl2);
    finalize_kernel<<<16, 256, 0, stream>>>(ptl2, out);
}